// Round 1
// baseline (5726.624 us; speedup 1.0000x reference)
//
#include <hip/hip_runtime.h>
#include <math.h>

#define BSZ 1024
#define SLEN 32
#define TLEN 32
#define EDIM 128
#define HE 256
#define VTOK 256

__device__ __forceinline__ float sgm(float x) { return 1.0f / (1.0f + expf(-x)); }

// ---------------- gi tables: tab[v][g] = bih[g] + emb[v]@Wih[g,:E] ----------------
__global__ __launch_bounds__(256) void k_gi_table(const float* __restrict__ emb,
                                                  const float* __restrict__ Wih, int ldw,
                                                  const float* __restrict__ bih,
                                                  float* __restrict__ tab) {
  int v = blockIdx.x;
  int g = blockIdx.y * 256 + threadIdx.x;
  __shared__ float e[EDIM];
  if (threadIdx.x < EDIM) e[threadIdx.x] = emb[v * EDIM + threadIdx.x];
  __syncthreads();
  const float4* w4 = (const float4*)(Wih + (size_t)g * ldw);
  float acc = 0.f;
#pragma unroll
  for (int j = 0; j < EDIM / 4; ++j) {
    float4 w = w4[j];
    acc += w.x * e[4 * j + 0] + w.y * e[4 * j + 1] + w.z * e[4 * j + 2] + w.w * e[4 * j + 3];
  }
  tab[(size_t)v * 768 + g] = acc + bih[g];
}

// ---------------- generic fp32 GEMM: out[m,n] = bias[n] + A[m,:K] . W[n,:K] -------
// 64x64 tile, 256 threads, 4x4 micro
__global__ __launch_bounds__(256) void k_gemm64(const float* __restrict__ A, int lda,
                                                const float* __restrict__ W, int ldw,
                                                const float* __restrict__ bias,
                                                float* __restrict__ out, int ldo, int K) {
  __shared__ float As[16][68];
  __shared__ float Bs[16][68];
  int m0 = blockIdx.x * 64, n0 = blockIdx.y * 64;
  int tid = threadIdx.x;
  int ty = tid >> 4, tx = tid & 15;
  float acc[4][4] = {};
  int lr = tid >> 2, lq = tid & 3;
  for (int k0 = 0; k0 < K; k0 += 16) {
    __syncthreads();
    {
      float4 a = *(const float4*)(A + (size_t)(m0 + lr) * lda + k0 + lq * 4);
      As[lq * 4 + 0][lr] = a.x; As[lq * 4 + 1][lr] = a.y;
      As[lq * 4 + 2][lr] = a.z; As[lq * 4 + 3][lr] = a.w;
      float4 b = *(const float4*)(W + (size_t)(n0 + lr) * ldw + k0 + lq * 4);
      Bs[lq * 4 + 0][lr] = b.x; Bs[lq * 4 + 1][lr] = b.y;
      Bs[lq * 4 + 2][lr] = b.z; Bs[lq * 4 + 3][lr] = b.w;
    }
    __syncthreads();
#pragma unroll
    for (int kk = 0; kk < 16; ++kk) {
      float4 av = *(const float4*)&As[kk][ty * 4];
      float4 bv = *(const float4*)&Bs[kk][tx * 4];
      float a[4] = {av.x, av.y, av.z, av.w};
      float b[4] = {bv.x, bv.y, bv.z, bv.w};
#pragma unroll
      for (int i = 0; i < 4; ++i)
#pragma unroll
        for (int j = 0; j < 4; ++j) acc[i][j] += a[i] * b[j];
    }
  }
  float4 bv = make_float4(0.f, 0.f, 0.f, 0.f);
  if (bias) bv = *(const float4*)&bias[n0 + tx * 4];
#pragma unroll
  for (int i = 0; i < 4; ++i) {
    float4 o;
    o.x = acc[i][0] + bv.x; o.y = acc[i][1] + bv.y;
    o.z = acc[i][2] + bv.z; o.w = acc[i][3] + bv.w;
    *(float4*)(out + (size_t)(m0 + ty * 4 + i) * ldo + n0 + tx * 4) = o;
  }
}

// 32x32 tile, 256 threads, 2x2 micro
__global__ __launch_bounds__(256) void k_gemm32(const float* __restrict__ A, int lda,
                                                const float* __restrict__ W, int ldw,
                                                const float* __restrict__ bias,
                                                float* __restrict__ out, int ldo, int K) {
  __shared__ float As[16][36];
  __shared__ float Bs[16][36];
  int m0 = blockIdx.x * 32, n0 = blockIdx.y * 32;
  int tid = threadIdx.x;
  int ty = tid >> 4, tx = tid & 15;
  float acc[2][2] = {};
  int lr = tid >> 2, lq = tid & 3;
  for (int k0 = 0; k0 < K; k0 += 16) {
    __syncthreads();
    if (tid < 128) {
      float4 a = *(const float4*)(A + (size_t)(m0 + lr) * lda + k0 + lq * 4);
      As[lq * 4 + 0][lr] = a.x; As[lq * 4 + 1][lr] = a.y;
      As[lq * 4 + 2][lr] = a.z; As[lq * 4 + 3][lr] = a.w;
      float4 b = *(const float4*)(W + (size_t)(n0 + lr) * ldw + k0 + lq * 4);
      Bs[lq * 4 + 0][lr] = b.x; Bs[lq * 4 + 1][lr] = b.y;
      Bs[lq * 4 + 2][lr] = b.z; Bs[lq * 4 + 3][lr] = b.w;
    }
    __syncthreads();
#pragma unroll
    for (int kk = 0; kk < 16; ++kk) {
      float2 av = *(const float2*)&As[kk][ty * 2];
      float2 bv = *(const float2*)&Bs[kk][tx * 2];
      acc[0][0] += av.x * bv.x; acc[0][1] += av.x * bv.y;
      acc[1][0] += av.y * bv.x; acc[1][1] += av.y * bv.y;
    }
  }
  float2 bv = make_float2(0.f, 0.f);
  if (bias) bv = *(const float2*)&bias[n0 + tx * 2];
#pragma unroll
  for (int i = 0; i < 2; ++i) {
    float2 o;
    o.x = acc[i][0] + bv.x; o.y = acc[i][1] + bv.y;
    *(float2*)(out + (size_t)(m0 + ty * 2 + i) * ldo + n0 + tx * 2) = o;
  }
}

// ---------------- encoder GRU step (both directions via blockIdx.z) ---------------
// enc_out layout: (B, S, 512); fwd writes cols [0,256), bwd writes cols [256,512)
__global__ __launch_bounds__(256) void k_gru_enc(float* __restrict__ enc_out,
                                                 const int* __restrict__ src,
                                                 const float* __restrict__ Whh_f,
                                                 const float* __restrict__ Whh_b,
                                                 const float* __restrict__ bhh_f,
                                                 const float* __restrict__ bhh_b,
                                                 const float* __restrict__ tab_f,
                                                 const float* __restrict__ tab_b, int s) {
  int dir = blockIdx.z;
  const float* Whh = dir ? Whh_b : Whh_f;
  const float* bhh = dir ? bhh_b : bhh_f;
  const float* tab = dir ? tab_b : tab_f;
  int s_store = dir ? (SLEN - 1 - s) : s;
  int s_prev = dir ? (s_store + 1) : (s_store - 1);
  int r0 = blockIdx.x * 64, c0 = blockIdx.y * 32;
  const float* hprev = enc_out + (size_t)s_prev * 512 + dir * 256;  // row stride 16384
  float* outp = enc_out + (size_t)s_store * 512 + dir * 256;
  int tid = threadIdx.x, tx = tid & 31, ty = tid >> 5;

  __shared__ float hs[32][68];
  __shared__ float wt[3][32][33];
  __shared__ int tokL[64];

  float accR[8] = {}, accZ[8] = {}, accN[8] = {};
  if (tid < 64) tokL[tid] = src[(size_t)(r0 + tid) * SLEN + s_store];

  if (s > 0) {
    for (int k0 = 0; k0 < 256; k0 += 32) {
      __syncthreads();
      for (int idx = tid; idx < 2048; idx += 256) {
        int r = idx >> 5, k = idx & 31;
        hs[k][r] = hprev[(size_t)(r0 + r) * 16384 + k0 + k];
      }
      for (int idx = tid; idx < 3072; idx += 256) {
        int g = idx >> 10, rem = idx & 1023;
        int c = rem >> 5, k = rem & 31;
        wt[g][k][c] = Whh[(size_t)(g * 256 + c0 + c) * 256 + k0 + k];
      }
      __syncthreads();
#pragma unroll
      for (int kk = 0; kk < 32; ++kk) {
        float wr = wt[0][kk][tx], wz = wt[1][kk][tx], wn = wt[2][kk][tx];
        float4 h0 = *(const float4*)&hs[kk][ty * 8];
        float4 h1 = *(const float4*)&hs[kk][ty * 8 + 4];
        float hv[8] = {h0.x, h0.y, h0.z, h0.w, h1.x, h1.y, h1.z, h1.w};
#pragma unroll
        for (int i = 0; i < 8; ++i) {
          accR[i] += hv[i] * wr; accZ[i] += hv[i] * wz; accN[i] += hv[i] * wn;
        }
      }
    }
  }
  __syncthreads();
  int gcol = c0 + tx;
  float bR = bhh[gcol], bZ = bhh[256 + gcol], bN = bhh[512 + gcol];
#pragma unroll
  for (int i = 0; i < 8; ++i) {
    int r = ty * 8 + i;
    int tok = tokL[r];
    const float* tb = tab + (size_t)tok * 768 + gcol;
    float giR = tb[0], giZ = tb[256], giN = tb[512];
    float hold = (s > 0) ? hprev[(size_t)(r0 + r) * 16384 + gcol] : 0.f;
    float rg = sgm(giR + accR[i] + bR);
    float zg = sgm(giZ + accZ[i] + bZ);
    float ng = tanhf(giN + rg * (accN[i] + bN));
    outp[(size_t)(r0 + r) * 16384 + gcol] = (1.f - zg) * ng + zg * hold;
  }
}

// ---------------- decoder GRU step: gh GEMM + table gi + aw@ecp, fused gates ------
__global__ __launch_bounds__(256) void k_gru_dec(const float* __restrict__ hprev,
                                                 const float* __restrict__ dWhh,
                                                 const float* __restrict__ dbhh,
                                                 const float* __restrict__ tabd,
                                                 const int* __restrict__ trg, int t,
                                                 const float* __restrict__ aw,
                                                 const float* __restrict__ ecp,
                                                 float* __restrict__ hnew) {
  int r0 = blockIdx.x * 64, c0 = blockIdx.y * 32;
  int tid = threadIdx.x, tx = tid & 31, ty = tid >> 5;
  __shared__ float hs[32][68];
  __shared__ float wt[3][32][33];
  __shared__ float awl[64][33];
  __shared__ int tokL[64];
  float accR[8] = {}, accZ[8] = {}, accN[8] = {};
  if (tid < 64) tokL[tid] = trg[(size_t)(r0 + tid) * TLEN + t];
  for (int idx = tid; idx < 2048; idx += 256) {
    int r = idx >> 5, sI = idx & 31;
    awl[r][sI] = aw[(size_t)(r0 + r) * SLEN + sI];
  }
  for (int k0 = 0; k0 < 256; k0 += 32) {
    __syncthreads();
    for (int idx = tid; idx < 2048; idx += 256) {
      int r = idx >> 5, k = idx & 31;
      hs[k][r] = hprev[(size_t)(r0 + r) * 256 + k0 + k];
    }
    for (int idx = tid; idx < 3072; idx += 256) {
      int g = idx >> 10, rem = idx & 1023;
      int c = rem >> 5, k = rem & 31;
      wt[g][k][c] = dWhh[(size_t)(g * 256 + c0 + c) * 256 + k0 + k];
    }
    __syncthreads();
#pragma unroll
    for (int kk = 0; kk < 32; ++kk) {
      float wr = wt[0][kk][tx], wz = wt[1][kk][tx], wn = wt[2][kk][tx];
      float4 h0 = *(const float4*)&hs[kk][ty * 8];
      float4 h1 = *(const float4*)&hs[kk][ty * 8 + 4];
      float hv[8] = {h0.x, h0.y, h0.z, h0.w, h1.x, h1.y, h1.z, h1.w};
#pragma unroll
      for (int i = 0; i < 8; ++i) {
        accR[i] += hv[i] * wr; accZ[i] += hv[i] * wz; accN[i] += hv[i] * wn;
      }
    }
  }
  __syncthreads();
  int gcol = c0 + tx;
  float bR = dbhh[gcol], bZ = dbhh[256 + gcol], bN = dbhh[512 + gcol];
#pragma unroll
  for (int i = 0; i < 8; ++i) {
    int r = ty * 8 + i;
    int row = r0 + r;
    int tok = tokL[r];
    const float* tb = tabd + (size_t)tok * 768 + gcol;
    float giR = tb[0], giZ = tb[256], giN = tb[512];
    const float* ep = ecp + (size_t)row * SLEN * 768 + gcol;
    float sR = 0.f, sZ = 0.f, sN = 0.f;
#pragma unroll 4
    for (int sI = 0; sI < 32; ++sI) {
      float a = awl[r][sI];
      const float* p = ep + (size_t)sI * 768;
      sR += a * p[0]; sZ += a * p[256]; sN += a * p[512];
    }
    giR += sR; giZ += sZ; giN += sN;
    float hold = hprev[(size_t)row * 256 + gcol];
    float rg = sgm(giR + accR[i] + bR);
    float zg = sgm(giZ + accZ[i] + bZ);
    float ng = tanhf(giN + rg * (accN[i] + bN));
    hnew[(size_t)row * 256 + gcol] = (1.f - zg) * ng + zg * hold;
  }
}

// ---------------- attention: scores + softmax -> aw (B,32) ------------------------
__global__ __launch_bounds__(256) void k_attn(const float* __restrict__ hWd,
                                              const float* __restrict__ enc_pre,
                                              const float* __restrict__ v_attn,
                                              float* __restrict__ aw) {
  int b = blockIdx.x;
  int tid = threadIdx.x;
  int s = tid >> 3, q = tid & 7;
  const float4* ep4 = (const float4*)(enc_pre + ((size_t)b * SLEN + s) * 256);
  const float4* hw4 = (const float4*)(hWd + (size_t)b * 256);
  const float4* vv4 = (const float4*)v_attn;
  float sum = 0.f;
#pragma unroll
  for (int j = 0; j < 8; ++j) {
    int idx = q * 8 + j;
    float4 e = ep4[idx];
    float4 h = hw4[idx];
    float4 v = vv4[idx];
    sum += tanhf(e.x + h.x) * v.x + tanhf(e.y + h.y) * v.y +
           tanhf(e.z + h.z) * v.z + tanhf(e.w + h.w) * v.w;
  }
  sum += __shfl_xor(sum, 1);
  sum += __shfl_xor(sum, 2);
  sum += __shfl_xor(sum, 4);
  __shared__ float sc[32];
  if (q == 0) sc[s] = sum;
  __syncthreads();
  if (tid < 32) {
    float v = sc[tid];
    float m = v;
#pragma unroll
    for (int off = 16; off >= 1; off >>= 1) m = fmaxf(m, __shfl_xor(m, off, 32));
    float e = expf(v - m);
    float ssum = e;
#pragma unroll
    for (int off = 16; off >= 1; off >>= 1) ssum += __shfl_xor(ssum, off, 32);
    aw[(size_t)b * SLEN + tid] = e / ssum;
  }
}

// ---------------- logits ctx part: out[b, v] += sum_s aw[b,s]*efp[b,s,v] ----------
__global__ __launch_bounds__(256) void k_awsum_add(const float* __restrict__ aw,
                                                   const float* __restrict__ efp,
                                                   float* __restrict__ outp) {
  int b = blockIdx.x, v = threadIdx.x;
  __shared__ float awl[32];
  if (v < 32) awl[v] = aw[(size_t)b * SLEN + v];
  __syncthreads();
  const float* ep = efp + (size_t)b * SLEN * VTOK + v;
  float acc = 0.f;
#pragma unroll
  for (int sI = 0; sI < 32; ++sI) acc += awl[sI] * ep[(size_t)sI * VTOK];
  float* o = outp + (size_t)b * (TLEN * VTOK) + v;
  *o += acc;
}

// ---------------- hcat = [hf | hb] ------------------------------------------------
__global__ __launch_bounds__(256) void k_hcat(const float* __restrict__ enc_out,
                                              float* __restrict__ hcat) {
  int b = blockIdx.x;
  int k = blockIdx.y * 256 + threadIdx.x;
  float v = (k < 256) ? enc_out[(size_t)b * 16384 + 31 * 512 + k]
                      : enc_out[(size_t)b * 16384 + k];
  hcat[(size_t)b * 512 + k] = v;
}

// ---------------- zero t=0 slice --------------------------------------------------
__global__ __launch_bounds__(256) void k_zero0(float* __restrict__ outp) {
  outp[(size_t)blockIdx.x * (TLEN * VTOK) + threadIdx.x] = 0.f;
}

extern "C" void kernel_launch(void* const* d_in, const int* in_sizes, int n_in,
                              void* d_out, int out_size, void* d_ws, size_t ws_size,
                              hipStream_t stream) {
  (void)in_sizes; (void)n_in; (void)out_size; (void)ws_size;
  const int* src = (const int*)d_in[0];
  const int* trg = (const int*)d_in[1];
  const float* enc_emb = (const float*)d_in[2];
  const float* eWih_f = (const float*)d_in[3];
  const float* eWhh_f = (const float*)d_in[4];
  const float* ebih_f = (const float*)d_in[5];
  const float* ebhh_f = (const float*)d_in[6];
  const float* eWih_b = (const float*)d_in[7];
  const float* eWhh_b = (const float*)d_in[8];
  const float* ebih_b = (const float*)d_in[9];
  const float* ebhh_b = (const float*)d_in[10];
  const float* Wproj = (const float*)d_in[11];
  const float* bproj = (const float*)d_in[12];
  const float* dec_emb = (const float*)d_in[13];
  const float* Wattn = (const float*)d_in[14];
  const float* battn = (const float*)d_in[15];
  const float* v_attn = (const float*)d_in[16];
  const float* dWih = (const float*)d_in[17];
  const float* dWhh = (const float*)d_in[18];
  const float* dbih = (const float*)d_in[19];
  const float* dbhh = (const float*)d_in[20];
  const float* Wfc = (const float*)d_in[21];
  const float* bfc = (const float*)d_in[22];
  float* dout = (float*)d_out;

  float* w = (float*)d_ws;
  float* enc_out = w;            w += (size_t)BSZ * SLEN * 512;   // 16,777,216
  float* enc_pre = w;            w += (size_t)BSZ * SLEN * 256;   //  8,388,608
  float* ecp = w;                w += (size_t)BSZ * SLEN * 768;   // 25,165,824
  float* efp = w;                w += (size_t)BSZ * SLEN * 256;   //  8,388,608
  float* tabf = w;               w += (size_t)64 * 768;
  float* tabb = w;               w += (size_t)64 * 768;
  float* tabd = w;               w += (size_t)256 * 768;
  float* hcat = w;               w += (size_t)BSZ * 512;
  float* h0 = w;                 w += (size_t)BSZ * 256;
  float* h1 = w;                 w += (size_t)BSZ * 256;
  float* hWdb = w;               w += (size_t)BSZ * 256;
  float* awb = w;                w += (size_t)BSZ * SLEN;

  // gi tables (bih folded in; bhh handled in GRU epilogue)
  k_gi_table<<<dim3(64, 3), 256, 0, stream>>>(enc_emb, eWih_f, EDIM, ebih_f, tabf);
  k_gi_table<<<dim3(64, 3), 256, 0, stream>>>(enc_emb, eWih_b, EDIM, ebih_b, tabb);
  k_gi_table<<<dim3(256, 3), 256, 0, stream>>>(dec_emb, dWih, 640, dbih, tabd);

  // bidirectional encoder, 32 sequential fused steps
  for (int s = 0; s < SLEN; ++s)
    k_gru_enc<<<dim3(16, 8, 2), 256, 0, stream>>>(enc_out, src, eWhh_f, eWhh_b, ebhh_f,
                                                  ebhh_b, tabf, tabb, s);

  // hdec = [hf|hb] @ Wproj.T + bproj
  k_hcat<<<dim3(BSZ, 2), 256, 0, stream>>>(enc_out, hcat);
  k_gemm32<<<dim3(BSZ / 32, 256 / 32), 256, 0, stream>>>(hcat, 512, Wproj, 512, bproj, h0,
                                                         256, 512);

  // projections of enc_out (M = 32768, K = 512)
  k_gemm64<<<dim3(512, 4), 256, 0, stream>>>(enc_out, 512, Wattn + 256, 768, battn,
                                             enc_pre, 256, 512);
  k_gemm64<<<dim3(512, 12), 256, 0, stream>>>(enc_out, 512, dWih + 128, 640, nullptr, ecp,
                                              768, 512);
  k_gemm64<<<dim3(512, 4), 256, 0, stream>>>(enc_out, 512, Wfc + 256, 768, nullptr, efp,
                                             256, 512);

  k_zero0<<<dim3(BSZ), 256, 0, stream>>>(dout);

  // decoder: 31 sequential steps
  for (int t = 0; t < TLEN - 1; ++t) {
    float* hc = (t & 1) ? h1 : h0;
    float* hn = (t & 1) ? h0 : h1;
    k_gemm32<<<dim3(32, 8), 256, 0, stream>>>(hc, 256, Wattn, 768, nullptr, hWdb, 256, 256);
    k_attn<<<dim3(BSZ), 256, 0, stream>>>(hWdb, enc_pre, v_attn, awb);
    k_gru_dec<<<dim3(16, 8), 256, 0, stream>>>(hc, dWhh, dbhh, tabd, trg, t, awb, ecp, hn);
    k_gemm32<<<dim3(32, 8), 256, 0, stream>>>(hn, 256, Wfc, 768, bfc, dout + (t + 1) * VTOK,
                                              TLEN * VTOK, 256);
    k_awsum_add<<<dim3(BSZ), 256, 0, stream>>>(awb, efp, dout + (t + 1) * VTOK);
  }
}

// Round 3
// 2521.367 us; speedup vs baseline: 2.2712x; 2.2712x over previous
//
#include <hip/hip_runtime.h>
#include <math.h>

#define BSZ 1024
#define SLEN 32
#define TLEN 32
#define EDIM 128
#define VTOKP 256

typedef unsigned short u16;
typedef __attribute__((ext_vector_type(8))) short bf16x8;
typedef __attribute__((ext_vector_type(4))) float f32x4;

__device__ __forceinline__ float sgm(float x) { return 1.0f / (1.0f + expf(-x)); }

__device__ __forceinline__ u16 f2b(float f) {
  union { float f; unsigned u; } v; v.f = f;
  unsigned r = v.u + 0x7fffu + ((v.u >> 16) & 1u);
  return (u16)(r >> 16);
}
__device__ __forceinline__ float b2f(u16 h) {
  union { unsigned u; float f; } v; v.u = ((unsigned)h) << 16; return v.f;
}

typedef __attribute__((address_space(1))) const void gv_t;
typedef __attribute__((address_space(3))) void lv_t;
__device__ __forceinline__ void gload16(const void* g, void* l) {
  __builtin_amdgcn_global_load_lds((gv_t*)g, (lv_t*)l, 16, 0, 0);
}

// ---------------- gi tables: tab[v][g] = bih[g] + emb[v]@Wih[g,:E] (fp32) ---------
__global__ __launch_bounds__(256) void k_gi_table(const float* __restrict__ emb,
                                                  const float* __restrict__ Wih, int ldw,
                                                  const float* __restrict__ bih,
                                                  float* __restrict__ tab) {
  int v = blockIdx.x;
  int g = blockIdx.y * 256 + threadIdx.x;
  __shared__ float e[EDIM];
  if (threadIdx.x < EDIM) e[threadIdx.x] = emb[v * EDIM + threadIdx.x];
  __syncthreads();
  const float4* w4 = (const float4*)(Wih + (size_t)g * ldw);
  float acc = 0.f;
#pragma unroll
  for (int j = 0; j < EDIM / 4; ++j) {
    float4 w = w4[j];
    acc += w.x * e[4 * j] + w.y * e[4 * j + 1] + w.z * e[4 * j + 2] + w.w * e[4 * j + 3];
  }
  tab[(size_t)v * 768 + g] = acc + bih[g];
}

// ---------------- fp32 -> bf16 weight pack: dst[r*n+c] = src[r*ld+off+c] ----------
__global__ __launch_bounds__(256) void k_pack(u16* __restrict__ dst,
                                              const float* __restrict__ src, int ld,
                                              int off, int n) {
  int r = blockIdx.x;
  for (int c = threadIdx.x; c < n; c += 256)
    dst[(size_t)r * n + c] = f2b(src[(size_t)r * ld + off + c]);
}

// gates B matrix (1024 x 768): rows 0-511 = [dWih_ctx | dWhh] (r,z gates);
// rows 512-767 = [dWih_ctx_n | 0]; rows 768-1023 = [0 | dWhh_n]
__global__ __launch_bounds__(256) void k_pack_gates(u16* __restrict__ Wg,
                                                    const float* __restrict__ dWih,
                                                    const float* __restrict__ dWhh) {
  int r = blockIdx.x;
  for (int c = threadIdx.x; c < 768; c += 256) {
    float v;
    if (r < 512)      v = (c < 512) ? dWih[(size_t)r * 640 + 128 + c] : dWhh[(size_t)r * 256 + (c - 512)];
    else if (r < 768) v = (c < 512) ? dWih[(size_t)r * 640 + 128 + c] : 0.f;
    else              v = (c < 512) ? 0.f : dWhh[(size_t)(r - 256) * 256 + (c - 512)];
    Wg[(size_t)r * 768 + c] = f2b(v);
  }
}

// ---------------- generic bf16 MFMA GEMM: out = A(MxK) . B(NxK)^T + bias ----------
// BM=128 BN=64 BK=64, 4 waves (2x2), swizzled LDS (rule 21: inv-swz source + swz read)
__global__ __launch_bounds__(256) void k_bgemm(const u16* __restrict__ A, int lda,
                                               const u16* __restrict__ B, int ldb,
                                               const float* __restrict__ bias,
                                               float* __restrict__ out, int ldo, int K) {
  __shared__ u16 sA[128 * 64];
  __shared__ u16 sB[64 * 64];
  int m0 = blockIdx.x * 128, n0 = blockIdx.y * 64;
  int tid = threadIdx.x, w = tid >> 6, l = tid & 63;
  int wr = w >> 1, wc = w & 1;
  f32x4 acc[4][2] = {};
  for (int k0 = 0; k0 < K; k0 += 64) {
    __syncthreads();
#pragma unroll
    for (int i = 0; i < 4; ++i) {
      int chunk = i * 4 + w;
      int d = chunk * 1024 + l * 16;
      int lg = d ^ (((d >> 7) & 7) << 4);
      int row = lg >> 7, kb = lg & 127;
      gload16((const char*)(A + (size_t)(m0 + row) * lda + k0) + kb, (char*)sA + chunk * 1024);
    }
#pragma unroll
    for (int i = 0; i < 2; ++i) {
      int chunk = i * 4 + w;
      int d = chunk * 1024 + l * 16;
      int lg = d ^ (((d >> 7) & 7) << 4);
      int row = lg >> 7, kb = lg & 127;
      gload16((const char*)(B + (size_t)(n0 + row) * ldb + k0) + kb, (char*)sB + chunk * 1024);
    }
    __syncthreads();
#pragma unroll
    for (int kk = 0; kk < 2; ++kk) {
      bf16x8 av[4], bv[2];
#pragma unroll
      for (int fm = 0; fm < 4; ++fm) {
        int row = wr * 64 + fm * 16 + (l & 15);
        int addr = (row * 128 + kk * 64 + (l >> 4) * 16) ^ ((row & 7) << 4);
        av[fm] = *(const bf16x8*)((const char*)sA + addr);
      }
#pragma unroll
      for (int fn = 0; fn < 2; ++fn) {
        int row = wc * 32 + fn * 16 + (l & 15);
        int addr = (row * 128 + kk * 64 + (l >> 4) * 16) ^ ((row & 7) << 4);
        bv[fn] = *(const bf16x8*)((const char*)sB + addr);
      }
#pragma unroll
      for (int fm = 0; fm < 4; ++fm)
#pragma unroll
        for (int fn = 0; fn < 2; ++fn)
          acc[fm][fn] = __builtin_amdgcn_mfma_f32_16x16x32_bf16(av[fm], bv[fn], acc[fm][fn], 0, 0, 0);
    }
  }
#pragma unroll
  for (int fn = 0; fn < 2; ++fn) {
    int c = n0 + wc * 32 + fn * 16 + (l & 15);
    float bb = bias ? bias[c] : 0.f;
#pragma unroll
    for (int fm = 0; fm < 4; ++fm) {
      int r = m0 + wr * 64 + fm * 16 + (l >> 4) * 4;
#pragma unroll
      for (int j = 0; j < 4; ++j)
        out[(size_t)(r + j) * ldo + c] = acc[fm][fn][j] + bb;
    }
  }
}

// ---------------- encoder GRU step, MFMA (both dirs via blockIdx.z) ---------------
// block: 64 rows x 32 gate-cols; 4 waves of 16 rows; 3 gate groups
__global__ __launch_bounds__(256) void k_genc(float* __restrict__ enc_out,
                                              u16* __restrict__ enc_b,
                                              const int* __restrict__ src,
                                              const u16* __restrict__ Whh_f,
                                              const u16* __restrict__ Whh_b,
                                              const float* __restrict__ bhh_f,
                                              const float* __restrict__ bhh_b,
                                              const float* __restrict__ tab_f,
                                              const float* __restrict__ tab_b, int s) {
  __shared__ u16 sA[64 * 64];
  __shared__ u16 sB[96 * 64];
  __shared__ int tokL[64];
  int dir = blockIdx.z;
  const u16* Whh = dir ? Whh_b : Whh_f;
  const float* bhh = dir ? bhh_b : bhh_f;
  const float* tab = dir ? tab_b : tab_f;
  int s_store = dir ? (SLEN - 1 - s) : s;
  int s_prev = dir ? (s_store + 1) : (s_store - 1);
  int m0 = blockIdx.x * 64, c0 = blockIdx.y * 32;
  int tid = threadIdx.x, w = tid >> 6, l = tid & 63;
  if (tid < 64) tokL[tid] = src[(size_t)(m0 + tid) * SLEN + s_store];
  __syncthreads();
  f32x4 acc[3][2] = {};
  if (s > 0) {
    const u16* hp = enc_b + (size_t)s_prev * 512 + dir * 256;  // row stride 16384
    for (int k0 = 0; k0 < 256; k0 += 64) {
      __syncthreads();
#pragma unroll
      for (int i = 0; i < 2; ++i) {
        int chunk = i * 4 + w;
        int d = chunk * 1024 + l * 16;
        int lg = d ^ (((d >> 7) & 7) << 4);
        int row = lg >> 7, kb = lg & 127;
        gload16((const char*)(hp + (size_t)(m0 + row) * 16384 + k0) + kb, (char*)sA + chunk * 1024);
      }
#pragma unroll
      for (int i = 0; i < 3; ++i) {
        int chunk = i * 4 + w;
        int d = chunk * 1024 + l * 16;
        int lg = d ^ (((d >> 7) & 7) << 4);
        int tr = lg >> 7, kb = lg & 127;
        int g = tr >> 5, cc = tr & 31;
        gload16((const char*)(Whh + (size_t)(g * 256 + c0 + cc) * 256 + k0) + kb,
                (char*)sB + chunk * 1024);
      }
      __syncthreads();
#pragma unroll
      for (int kk = 0; kk < 2; ++kk) {
        int arow = w * 16 + (l & 15);
        int aaddr = (arow * 128 + kk * 64 + (l >> 4) * 16) ^ ((arow & 7) << 4);
        bf16x8 av = *(const bf16x8*)((const char*)sA + aaddr);
#pragma unroll
        for (int g = 0; g < 3; ++g)
#pragma unroll
          for (int fn = 0; fn < 2; ++fn) {
            int br = g * 32 + fn * 16 + (l & 15);
            int baddr = (br * 128 + kk * 64 + (l >> 4) * 16) ^ ((br & 7) << 4);
            bf16x8 bv = *(const bf16x8*)((const char*)sB + baddr);
            acc[g][fn] = __builtin_amdgcn_mfma_f32_16x16x32_bf16(av, bv, acc[g][fn], 0, 0, 0);
          }
      }
    }
  }
#pragma unroll
  for (int fn = 0; fn < 2; ++fn) {
    int c = c0 + fn * 16 + (l & 15);
    float bR = bhh[c], bZ = bhh[256 + c], bN = bhh[512 + c];
#pragma unroll
    for (int j = 0; j < 4; ++j) {
      int rr = w * 16 + (l >> 4) * 4 + j;
      int row = m0 + rr;
      const float* tb = tab + (size_t)tokL[rr] * 768 + c;
      float hold = (s > 0) ? enc_out[((size_t)row * SLEN + s_prev) * 512 + dir * 256 + c] : 0.f;
      float rg = sgm(tb[0] + acc[0][fn][j] + bR);
      float zg = sgm(tb[256] + acc[1][fn][j] + bZ);
      float ng = tanhf(tb[512] + rg * (acc[2][fn][j] + bN));
      float hn = (1.f - zg) * ng + zg * hold;
      size_t oi = ((size_t)row * SLEN + s_store) * 512 + dir * 256 + c;
      enc_out[oi] = hn;
      enc_b[oi] = f2b(hn);
    }
  }
}

// ---------------- decoder gates, MFMA: A=cat(1024x768) B=Wg(1024x768) -------------
// block: 64 rows x 32 gate-cols; 4 gate groups (R, Z, Ni, Nh)
__global__ __launch_bounds__(256) void k_gates(const u16* __restrict__ cat,
                                               const u16* __restrict__ Wg,
                                               const float* __restrict__ tabd,
                                               const float* __restrict__ dbhh,
                                               const int* __restrict__ trg, int t,
                                               const float* __restrict__ hprev,
                                               float* __restrict__ hnew,
                                               u16* __restrict__ cat_nxt,
                                               u16* __restrict__ lcat) {
  __shared__ u16 sA[64 * 64];
  __shared__ u16 sB[128 * 64];
  __shared__ int tokL[64];
  int m0 = blockIdx.x * 64, c0 = blockIdx.y * 32;
  int tid = threadIdx.x, w = tid >> 6, l = tid & 63;
  if (tid < 64) tokL[tid] = trg[(size_t)(m0 + tid) * TLEN + t];
  f32x4 acc[4][2] = {};
  for (int k0 = 0; k0 < 768; k0 += 64) {
    __syncthreads();
#pragma unroll
    for (int i = 0; i < 2; ++i) {
      int chunk = i * 4 + w;
      int d = chunk * 1024 + l * 16;
      int lg = d ^ (((d >> 7) & 7) << 4);
      int row = lg >> 7, kb = lg & 127;
      gload16((const char*)(cat + (size_t)(m0 + row) * 768 + k0) + kb, (char*)sA + chunk * 1024);
    }
#pragma unroll
    for (int i = 0; i < 4; ++i) {
      int chunk = i * 4 + w;
      int d = chunk * 1024 + l * 16;
      int lg = d ^ (((d >> 7) & 7) << 4);
      int tr = lg >> 7, kb = lg & 127;
      int g = tr >> 5, cc = tr & 31;
      gload16((const char*)(Wg + (size_t)(g * 256 + c0 + cc) * 768 + k0) + kb,
              (char*)sB + chunk * 1024);
    }
    __syncthreads();
#pragma unroll
    for (int kk = 0; kk < 2; ++kk) {
      int arow = w * 16 + (l & 15);
      int aaddr = (arow * 128 + kk * 64 + (l >> 4) * 16) ^ ((arow & 7) << 4);
      bf16x8 av = *(const bf16x8*)((const char*)sA + aaddr);
#pragma unroll
      for (int g = 0; g < 4; ++g)
#pragma unroll
        for (int fn = 0; fn < 2; ++fn) {
          int br = g * 32 + fn * 16 + (l & 15);
          int baddr = (br * 128 + kk * 64 + (l >> 4) * 16) ^ ((br & 7) << 4);
          bf16x8 bv = *(const bf16x8*)((const char*)sB + baddr);
          acc[g][fn] = __builtin_amdgcn_mfma_f32_16x16x32_bf16(av, bv, acc[g][fn], 0, 0, 0);
        }
    }
  }
#pragma unroll
  for (int fn = 0; fn < 2; ++fn) {
    int c = c0 + fn * 16 + (l & 15);
    float bR = dbhh[c], bZ = dbhh[256 + c], bN = dbhh[512 + c];
#pragma unroll
    for (int j = 0; j < 4; ++j) {
      int rr = w * 16 + (l >> 4) * 4 + j;
      int row = m0 + rr;
      const float* tb = tabd + (size_t)tokL[rr] * 768 + c;
      float rg = sgm(tb[0] + acc[0][fn][j] + bR);
      float zg = sgm(tb[256] + acc[1][fn][j] + bZ);
      float ng = tanhf(tb[512] + acc[2][fn][j] + rg * (acc[3][fn][j] + bN));
      float hold = hprev[(size_t)row * 256 + c];
      float hn = (1.f - zg) * ng + zg * hold;
      hnew[(size_t)row * 256 + c] = hn;
      u16 hb = f2b(hn);
      cat_nxt[(size_t)row * 768 + 512 + c] = hb;
      lcat[(size_t)row * 768 + c] = hb;
    }
  }
}

// ---------------- ctx = aw @ enc_out_b -> bf16 into cat[0:512] & lcat[256:768] ----
__global__ __launch_bounds__(256) void k_ctx(const float* __restrict__ aw,
                                             const u16* __restrict__ enc_b,
                                             u16* __restrict__ cat_cur,
                                             u16* __restrict__ lcat) {
  __shared__ float awl[64][33];
  int r0 = blockIdx.x * 64, c0 = blockIdx.y * 64;
  int tid = threadIdx.x;
  for (int idx = tid; idx < 2048; idx += 256) {
    int r = idx >> 5, s = idx & 31;
    awl[r][s] = aw[(size_t)(r0 + r) * SLEN + s];
  }
  __syncthreads();
  int tx = tid & 31, ty = tid >> 5;
  int c = c0 + tx * 2;
#pragma unroll
  for (int i = 0; i < 8; ++i) {
    int r = ty + i * 8;
    int row = r0 + r;
    float ax = 0.f, ay = 0.f;
#pragma unroll 8
    for (int s = 0; s < 32; ++s) {
      float a = awl[r][s];
      unsigned pk = *(const unsigned*)(enc_b + ((size_t)row * SLEN + s) * 512 + c);
      ax += a * b2f((u16)(pk & 0xffff));
      ay += a * b2f((u16)(pk >> 16));
    }
    unsigned o = (unsigned)f2b(ax) | ((unsigned)f2b(ay) << 16);
    *(unsigned*)(cat_cur + (size_t)row * 768 + c) = o;
    *(unsigned*)(lcat + (size_t)row * 768 + 256 + c) = o;
  }
}

// ---------------- fp32 GEMM 32x32 (kept for hdec / hWd) --------------------------
__global__ __launch_bounds__(256) void k_gemm32(const float* __restrict__ A, int lda,
                                                const float* __restrict__ W, int ldw,
                                                const float* __restrict__ bias,
                                                float* __restrict__ out, int ldo, int K) {
  __shared__ float As[16][36];
  __shared__ float Bs[16][36];
  int m0 = blockIdx.x * 32, n0 = blockIdx.y * 32;
  int tid = threadIdx.x;
  int ty = tid >> 4, tx = tid & 15;
  float acc[2][2] = {};
  int lr = tid >> 2, lq = tid & 3;
  for (int k0 = 0; k0 < K; k0 += 16) {
    __syncthreads();
    if (tid < 128) {
      float4 a = *(const float4*)(A + (size_t)(m0 + lr) * lda + k0 + lq * 4);
      As[lq * 4 + 0][lr] = a.x; As[lq * 4 + 1][lr] = a.y;
      As[lq * 4 + 2][lr] = a.z; As[lq * 4 + 3][lr] = a.w;
      float4 b = *(const float4*)(W + (size_t)(n0 + lr) * ldw + k0 + lq * 4);
      Bs[lq * 4 + 0][lr] = b.x; Bs[lq * 4 + 1][lr] = b.y;
      Bs[lq * 4 + 2][lr] = b.z; Bs[lq * 4 + 3][lr] = b.w;
    }
    __syncthreads();
#pragma unroll
    for (int kk = 0; kk < 16; ++kk) {
      float2 av = *(const float2*)&As[kk][ty * 2];
      float2 bv = *(const float2*)&Bs[kk][tx * 2];
      acc[0][0] += av.x * bv.x; acc[0][1] += av.x * bv.y;
      acc[1][0] += av.y * bv.x; acc[1][1] += av.y * bv.y;
    }
  }
  float2 bv = make_float2(0.f, 0.f);
  if (bias) bv = *(const float2*)&bias[n0 + tx * 2];
#pragma unroll
  for (int i = 0; i < 2; ++i) {
    float2 o;
    o.x = acc[i][0] + bv.x; o.y = acc[i][1] + bv.y;
    *(float2*)(out + (size_t)(m0 + ty * 2 + i) * ldo + n0 + tx * 2) = o;
  }
}

// ---------------- attention: scores + softmax -> aw (B,32) ------------------------
__global__ __launch_bounds__(256) void k_attn(const float* __restrict__ hWd,
                                              const float* __restrict__ enc_pre,
                                              const float* __restrict__ v_attn,
                                              float* __restrict__ aw) {
  int b = blockIdx.x;
  int tid = threadIdx.x;
  int s = tid >> 3, q = tid & 7;
  const float4* ep4 = (const float4*)(enc_pre + ((size_t)b * SLEN + s) * 256);
  const float4* hw4 = (const float4*)(hWd + (size_t)b * 256);
  const float4* vv4 = (const float4*)v_attn;
  float sum = 0.f;
#pragma unroll
  for (int j = 0; j < 8; ++j) {
    int idx = q * 8 + j;
    float4 e = ep4[idx];
    float4 h = hw4[idx];
    float4 v = vv4[idx];
    sum += tanhf(e.x + h.x) * v.x + tanhf(e.y + h.y) * v.y +
           tanhf(e.z + h.z) * v.z + tanhf(e.w + h.w) * v.w;
  }
  sum += __shfl_xor(sum, 1);
  sum += __shfl_xor(sum, 2);
  sum += __shfl_xor(sum, 4);
  __shared__ float sc[32];
  if (q == 0) sc[s] = sum;
  __syncthreads();
  if (tid < 32) {
    float v = sc[tid];
    float m = v;
#pragma unroll
    for (int off = 16; off >= 1; off >>= 1) m = fmaxf(m, __shfl_xor(m, off, 32));
    float e = expf(v - m);
    float ssum = e;
#pragma unroll
    for (int off = 16; off >= 1; off >>= 1) ssum += __shfl_xor(ssum, off, 32);
    aw[(size_t)b * SLEN + tid] = e / ssum;
  }
}

// ---------------- hcat = [hf | hb] ------------------------------------------------
__global__ __launch_bounds__(256) void k_hcat(const float* __restrict__ enc_out,
                                              float* __restrict__ hcat) {
  int b = blockIdx.x;
  int k = blockIdx.y * 256 + threadIdx.x;
  float v = (k < 256) ? enc_out[(size_t)b * 16384 + 31 * 512 + k]
                      : enc_out[(size_t)b * 16384 + k];
  hcat[(size_t)b * 512 + k] = v;
}

// ---------------- h0 fp32 -> bf16 into cat0[512:768] ------------------------------
__global__ __launch_bounds__(256) void k_h2b(const float* __restrict__ h,
                                             u16* __restrict__ cat0) {
  int row = blockIdx.x, c = threadIdx.x;
  cat0[(size_t)row * 768 + 512 + c] = f2b(h[(size_t)row * 256 + c]);
}

// ---------------- zero t=0 slice --------------------------------------------------
__global__ __launch_bounds__(256) void k_zero0(float* __restrict__ outp) {
  outp[(size_t)blockIdx.x * (TLEN * VTOKP) + threadIdx.x] = 0.f;
}

extern "C" void kernel_launch(void* const* d_in, const int* in_sizes, int n_in,
                              void* d_out, int out_size, void* d_ws, size_t ws_size,
                              hipStream_t stream) {
  (void)in_sizes; (void)n_in; (void)out_size; (void)ws_size;
  const int* src = (const int*)d_in[0];
  const int* trg = (const int*)d_in[1];
  const float* enc_emb = (const float*)d_in[2];
  const float* eWih_f = (const float*)d_in[3];
  const float* eWhh_f = (const float*)d_in[4];
  const float* ebih_f = (const float*)d_in[5];
  const float* ebhh_f = (const float*)d_in[6];
  const float* eWih_b = (const float*)d_in[7];
  const float* eWhh_b = (const float*)d_in[8];
  const float* ebih_b = (const float*)d_in[9];
  const float* ebhh_b = (const float*)d_in[10];
  const float* Wproj = (const float*)d_in[11];
  const float* bproj = (const float*)d_in[12];
  const float* dec_emb = (const float*)d_in[13];
  const float* Wattn = (const float*)d_in[14];
  const float* battn = (const float*)d_in[15];
  const float* v_attn = (const float*)d_in[16];
  const float* dWih = (const float*)d_in[17];
  const float* dWhh = (const float*)d_in[18];
  const float* dbih = (const float*)d_in[19];
  const float* dbhh = (const float*)d_in[20];
  const float* Wfc = (const float*)d_in[21];
  const float* bfc = (const float*)d_in[22];
  float* dout = (float*)d_out;

  char* base = (char*)d_ws;
  size_t off = 0;
  auto alloc = [&](size_t bytes) {
    void* p = base + off;
    off += (bytes + 255) & ~(size_t)255;
    return p;
  };
  float* enc_out = (float*)alloc((size_t)BSZ * SLEN * 512 * 4);
  u16* enc_b     = (u16*)alloc((size_t)BSZ * SLEN * 512 * 2);
  float* enc_pre = (float*)alloc((size_t)BSZ * SLEN * 256 * 4);
  float* tabf    = (float*)alloc((size_t)64 * 768 * 4);
  float* tabb    = (float*)alloc((size_t)64 * 768 * 4);
  float* tabd    = (float*)alloc((size_t)256 * 768 * 4);
  float* hcat    = (float*)alloc((size_t)BSZ * 512 * 4);
  float* h0      = (float*)alloc((size_t)BSZ * 256 * 4);
  float* h1      = (float*)alloc((size_t)BSZ * 256 * 4);
  float* hWdb    = (float*)alloc((size_t)BSZ * 256 * 4);
  float* awb     = (float*)alloc((size_t)BSZ * SLEN * 4);
  u16* Whhf_b    = (u16*)alloc((size_t)768 * 256 * 2);
  u16* Whhb_b    = (u16*)alloc((size_t)768 * 256 * 2);
  u16* We_b      = (u16*)alloc((size_t)256 * 512 * 2);
  u16* Wg        = (u16*)alloc((size_t)1024 * 768 * 2);
  u16* Wfc_b     = (u16*)alloc((size_t)256 * 768 * 2);
  u16* cat0      = (u16*)alloc((size_t)BSZ * 768 * 2);
  u16* cat1      = (u16*)alloc((size_t)BSZ * 768 * 2);
  u16* lcat      = (u16*)alloc((size_t)BSZ * 768 * 2);

  // tables + weight packs
  k_gi_table<<<dim3(64, 3), 256, 0, stream>>>(enc_emb, eWih_f, EDIM, ebih_f, tabf);
  k_gi_table<<<dim3(64, 3), 256, 0, stream>>>(enc_emb, eWih_b, EDIM, ebih_b, tabb);
  k_gi_table<<<dim3(256, 3), 256, 0, stream>>>(dec_emb, dWih, 640, dbih, tabd);
  k_pack<<<dim3(768), 256, 0, stream>>>(Whhf_b, eWhh_f, 256, 0, 256);
  k_pack<<<dim3(768), 256, 0, stream>>>(Whhb_b, eWhh_b, 256, 0, 256);
  k_pack<<<dim3(256), 256, 0, stream>>>(We_b, Wattn, 768, 256, 512);
  k_pack<<<dim3(256), 256, 0, stream>>>(Wfc_b, Wfc, 768, 0, 768);
  k_pack_gates<<<dim3(1024), 256, 0, stream>>>(Wg, dWih, dWhh);

  // bidirectional encoder, 32 sequential MFMA steps
  for (int s = 0; s < SLEN; ++s)
    k_genc<<<dim3(16, 8, 2), 256, 0, stream>>>(enc_out, enc_b, src, Whhf_b, Whhb_b,
                                               ebhh_f, ebhh_b, tabf, tabb, s);

  // hdec = [hf|hb] @ Wproj.T + bproj  (fp32), then bf16 copy into cat0
  k_hcat<<<dim3(BSZ, 2), 256, 0, stream>>>(enc_out, hcat);
  k_gemm32<<<dim3(BSZ / 32, 8), 256, 0, stream>>>(hcat, 512, Wproj, 512, bproj, h0, 256, 512);
  k_h2b<<<dim3(BSZ), 256, 0, stream>>>(h0, cat0);

  // enc_pre = enc_out @ We.T + battn  (bf16 MFMA)
  k_bgemm<<<dim3(256, 4), 256, 0, stream>>>(enc_b, 512, We_b, 512, battn, enc_pre, 256, 512);

  k_zero0<<<dim3(BSZ), 256, 0, stream>>>(dout);

  // decoder: 31 sequential steps
  for (int t = 0; t < TLEN - 1; ++t) {
    float* hc = (t & 1) ? h1 : h0;
    float* hn = (t & 1) ? h0 : h1;
    u16* cc = (t & 1) ? cat1 : cat0;
    u16* cn = (t & 1) ? cat0 : cat1;
    k_gemm32<<<dim3(32, 8), 256, 0, stream>>>(hc, 256, Wattn, 768, nullptr, hWdb, 256, 256);
    k_attn<<<dim3(BSZ), 256, 0, stream>>>(hWdb, enc_pre, v_attn, awb);
    k_ctx<<<dim3(16, 8), 256, 0, stream>>>(awb, enc_b, cc, lcat);
    k_gates<<<dim3(16, 8), 256, 0, stream>>>(cc, Wg, tabd, dbhh, trg, t, hc, hn, cn, lcat);
    k_bgemm<<<dim3(8, 4), 256, 0, stream>>>(lcat, 768, Wfc_b, 768, bfc,
                                            dout + (size_t)(t + 1) * 256, TLEN * 256, 768);
  }
}